// Round 7
// baseline (76.549 us; speedup 1.0000x reference)
//
#include <hip/hip_runtime.h>
#include <hip/hip_bf16.h>
#include <math.h>

// B=2, S=1024, D=512, H=8, hd=64.  M = B*S = 2048.
// Chunked causal linear attention, chunk C=128, NC=8, BH=16.
// 5 launches: prep -> qkv+xg GEMM -> mc -> attn(256 blks) -> projgate(fused).

typedef __bf16 bf16x8 __attribute__((ext_vector_type(8)));
typedef __bf16 bf16x4 __attribute__((ext_vector_type(4)));
typedef float f32x4 __attribute__((ext_vector_type(4)));

#define MFMA16(a, b, c) __builtin_amdgcn_mfma_f32_16x16x32_bf16(a, b, c, 0, 0, 0)

__device__ __forceinline__ float elu1(float v) { return v > 0.f ? v + 1.f : __expf(v); }

__device__ __forceinline__ void gload16(const void* g, void* l) {
    __builtin_amdgcn_global_load_lds((const __attribute__((address_space(1))) void*)g,
                                     (__attribute__((address_space(3))) void*)l, 16, 0, 0);
}

// ---------------------------------------------------------------- prep
// z=0..3: 512x512 transpose {Wq,Wk,Wv,Wo}; z=4: Wg 1024x512 split -> wg1T (into wqkvgT) + wg2T;
// z=5: x -> bf16
__global__ __launch_bounds__(256) void prep_kernel(
    const float* __restrict__ x, const float* __restrict__ Wq, const float* __restrict__ Wk,
    const float* __restrict__ Wv, const float* __restrict__ Wo, const float* __restrict__ Wg,
    __bf16* __restrict__ xb, __bf16* __restrict__ wqkvgT, __bf16* __restrict__ woT,
    __bf16* __restrict__ wg2T) {
    int z = blockIdx.z;
    if (z == 5) {
        int bid = blockIdx.y * 16 + blockIdx.x;
        int base = (bid * 256 + threadIdx.x) * 8;
        bf16x8 o;
#pragma unroll
        for (int j = 0; j < 8; j++) o[j] = (__bf16)x[base + j];
        *(bf16x8*)&xb[base] = o;
        return;
    }
    const float* in;
    int R = 512;
    if (z == 0) in = Wq;
    else if (z == 1) in = Wk;
    else if (z == 2) in = Wv;
    else if (z == 3) in = Wo;
    else { in = Wg; R = 1024; }
    if ((int)blockIdx.y * 32 >= R) return;
    __shared__ float t[32][33];
    int bx = blockIdx.x, by = blockIdx.y;
    int tx = threadIdx.x & 31, ty = threadIdx.x >> 5;
#pragma unroll
    for (int i = 0; i < 32; i += 8)
        t[ty + i][tx] = in[(size_t)(by * 32 + ty + i) * 512 + bx * 32 + tx];
    __syncthreads();
#pragma unroll
    for (int i = 0; i < 32; i += 8) {
        int n = bx * 32 + ty + i;     // output row (col of W)
        int kk = by * 32 + tx;        // output col (row of W)
        __bf16 val = (__bf16)t[tx][ty + i];
        if (z == 0) wqkvgT[(size_t)n * 512 + kk] = val;
        else if (z == 1) wqkvgT[(size_t)(512 + n) * 512 + kk] = val;
        else if (z == 2) wqkvgT[(size_t)(1024 + n) * 512 + kk] = val;
        else if (z == 3) woT[(size_t)n * 512 + kk] = val;
        else if (kk < 512) wqkvgT[(size_t)(1536 + n) * 512 + kk] = val;
        else wg2T[(size_t)n * 512 + (kk - 512)] = val;
    }
}

// ---------------------------------------------------------------- qkv+xg GEMM (64x128 tile, BK=32, 3-deep counted-vmcnt)
// A = xb [2048][512]; Bw = wqkvgT [2048 n][512 k]. N cols: 0-511 q, 512-1023 k, 1024-1535 v, 1536-2047 xg.
__global__ __launch_bounds__(256) void qkv_kernel(
    const __bf16* __restrict__ A, const __bf16* __restrict__ Bw,
    __bf16* __restrict__ q_out, __bf16* __restrict__ k_out,
    __bf16* __restrict__ kt_out, __bf16* __restrict__ vt_out, float* __restrict__ xg) {
    constexpr int BM = 64, BN = 128;
    constexpr int MI = 2, NI = 4;
    __shared__ __bf16 sA[3 * BM * 32];
    __shared__ __bf16 sB[3 * BN * 32];
    int bm = blockIdx.x, bn = blockIdx.y;
    int tid = threadIdx.x, w = tid >> 6, l = tid & 63;
    int wr = (w >> 1) * 32, wc = (w & 1) * 64;
    int r = tid >> 2, c = (tid & 3) * 8;
    f32x4 acc[MI][NI] = {};
    const int nt = 16;

    auto stage = [&](int t, int buf) {
        int k0 = t * 32;
        gload16(&A[(size_t)(bm * BM + r) * 512 + k0 + c], &sA[buf * 2048 + w * 512]);
#pragma unroll
        for (int i = 0; i < 2; i++)
            gload16(&Bw[(size_t)(bn * BN + i * 64 + r) * 512 + k0 + c],
                    &sB[buf * 4096 + i * 2048 + w * 512]);
    };

    stage(0, 0);
    stage(1, 1);
    for (int t = 0; t < nt; t++) {
        if (t + 1 < nt) asm volatile("s_waitcnt vmcnt(3)" ::: "memory");
        else asm volatile("s_waitcnt vmcnt(0)" ::: "memory");
        asm volatile("s_barrier" ::: "memory");
        if (t + 2 < nt) stage(t + 2, (t + 2) % 3);
        int buf = t % 3;
        bf16x8 af[MI], bfr[NI];
#pragma unroll
        for (int mi = 0; mi < MI; mi++)
            af[mi] = *(const bf16x8*)&sA[buf * 2048 + (wr + mi * 16 + (l & 15)) * 32 + ((l >> 4) << 3)];
#pragma unroll
        for (int ni = 0; ni < NI; ni++)
            bfr[ni] = *(const bf16x8*)&sB[buf * 4096 + (wc + ni * 16 + (l & 15)) * 32 + ((l >> 4) << 3)];
#pragma unroll
        for (int mi = 0; mi < MI; mi++)
#pragma unroll
            for (int ni = 0; ni < NI; ni++)
                acc[mi][ni] = MFMA16(af[mi], bfr[ni], acc[mi][ni]);
    }

#pragma unroll
    for (int mi = 0; mi < MI; mi++) {
        int gm0 = bm * BM + wr + mi * 16 + ((l >> 4) << 2);
        int b = gm0 >> 10, s0 = gm0 & 1023;
#pragma unroll
        for (int ni = 0; ni < NI; ni++) {
            int gn = bn * BN + wc + ni * 16 + (l & 15);
            int which = gn >> 9, h = (gn >> 6) & 7, d = gn & 63;
            int bh = b * 8 + h;
            if (which == 0) {
#pragma unroll
                for (int j = 0; j < 4; j++)
                    q_out[((size_t)(bh * 1024 + s0 + j)) * 64 + d] = (__bf16)elu1(acc[mi][ni][j]);
            } else if (which == 1) {
                bf16x4 pk;
#pragma unroll
                for (int j = 0; j < 4; j++) {
                    __bf16 tb = (__bf16)elu1(acc[mi][ni][j]);
                    pk[j] = tb;
                    k_out[((size_t)(bh * 1024 + s0 + j)) * 64 + d] = tb;
                }
                *(bf16x4*)&kt_out[((size_t)(bh * 64 + d)) * 1024 + s0] = pk;
            } else if (which == 2) {
                bf16x4 pv;
#pragma unroll
                for (int j = 0; j < 4; j++) pv[j] = (__bf16)acc[mi][ni][j];
                *(bf16x4*)&vt_out[((size_t)(bh * 64 + d)) * 1024 + s0] = pv;
            } else {
#pragma unroll
                for (int j = 0; j < 4; j++)
                    xg[(size_t)(gm0 + j) * 512 + (gn & 511)] = acc[mi][ni][j];
            }
        }
    }
}

// ---------------------------------------------------------------- per-chunk M_c = V^T K + ksum_c (128 blocks)
__global__ __launch_bounds__(256) void mc_kernel(const __bf16* __restrict__ ktb,
                                                 const __bf16* __restrict__ vtb,
                                                 float* __restrict__ Mc, float* __restrict__ ksc) {
    int blk = blockIdx.x;
    int bh = blk >> 3, ch = blk & 7;
    int tid = threadIdx.x, w = tid >> 6, l = tid & 63;
    const __bf16* vb = vtb + (size_t)bh * 65536 + ch * 128;
    const __bf16* kp = ktb + (size_t)bh * 65536 + ch * 128;
    f32x4 macc[4] = {};
#pragma unroll
    for (int ks = 0; ks < 4; ks++) {
        bf16x8 a = *(const bf16x8*)&vb[(size_t)(w * 16 + (l & 15)) * 1024 + ks * 32 + ((l >> 4) << 3)];
#pragma unroll
        for (int ni = 0; ni < 4; ni++) {
            bf16x8 bb = *(const bf16x8*)&kp[(size_t)(ni * 16 + (l & 15)) * 1024 + ks * 32 + ((l >> 4) << 3)];
            macc[ni] = MFMA16(a, bb, macc[ni]);
        }
    }
    float* mout = Mc + (size_t)blk * 4096;
#pragma unroll
    for (int ni = 0; ni < 4; ni++)
#pragma unroll
        for (int j = 0; j < 4; j++)
            mout[(size_t)(w * 16 + ((l >> 4) << 2) + j) * 64 + ni * 16 + (l & 15)] = macc[ni][j];
    if (tid < 64) {
        float s = 0.f;
        const __bf16* kr = ktb + (size_t)(bh * 64 + tid) * 1024 + ch * 128;
#pragma unroll
        for (int t = 0; t < 16; t++) {
            bf16x8 v = *(const bf16x8*)&kr[t * 8];
#pragma unroll
            for (int j = 0; j < 8; j++) s += (float)v[j];
        }
        ksc[blk * 64 + tid] = s;
    }
}

// ---------------------------------------------------------------- attention: 256 blocks (bh, ch, half)
// Each block: 64 q-rows (half-chunk). Wave w owns local rows w*16..w*16+15, all 64 out cols.
__global__ __launch_bounds__(256) void attn_kernel(
    const __bf16* __restrict__ qb, const __bf16* __restrict__ kb,
    const __bf16* __restrict__ vtb, const float* __restrict__ Mc,
    const float* __restrict__ ksc, __bf16* __restrict__ attn_out) {
    int blk = blockIdx.x;
    int bh = blk >> 4, ch = (blk >> 1) & 7, half = blk & 1;
    int b = bh >> 3, h = bh & 7;
    int tid = threadIdx.x, w = tid >> 6, l = tid & 63;

    __shared__ __bf16 sQ[64 * 72];
    __shared__ __bf16 sP[64 * 136];
    __shared__ __bf16 sM[64 * 72];
    __shared__ float den[64];
    __shared__ float rsum[64];
    __shared__ float ksst[64];

    // ---- phase 0: stage Q (64 rows), sum prior Mc -> sM, ksum -> ksst
    const __bf16* qsrc = qb + (size_t)(bh * 1024 + ch * 128 + half * 64) * 64;
#pragma unroll
    for (int i = 0; i < 2; i++) {
        int e = i * 2048 + tid * 8;
        *(bf16x8*)&sQ[(e >> 6) * 72 + (e & 63)] = *(const bf16x8*)&qsrc[e];
    }
    {
        int r0 = tid >> 2, c0 = (tid & 3) * 16;
        f32x4 s0 = {}, s1 = {}, s2 = {}, s3 = {};
        const float* mcb = Mc + (size_t)(bh * 8) * 4096 + r0 * 64 + c0;
        for (int c = 0; c < ch; c++) {
            const float* p = mcb + (size_t)c * 4096;
            s0 += *(const f32x4*)&p[0];
            s1 += *(const f32x4*)&p[4];
            s2 += *(const f32x4*)&p[8];
            s3 += *(const f32x4*)&p[12];
        }
        __bf16* d = &sM[r0 * 72 + c0];
#pragma unroll
        for (int j = 0; j < 4; j++) {
            d[j] = (__bf16)s0[j];
            d[4 + j] = (__bf16)s1[j];
            d[8 + j] = (__bf16)s2[j];
            d[12 + j] = (__bf16)s3[j];
        }
    }
    if (tid < 64) {
        float s = 0.f;
        for (int c = 0; c < ch; c++) s += ksc[(bh * 8 + c) * 64 + tid];
        ksst[tid] = s;
    }
    __syncthreads();

    // ---- den (state denominator) for this block's 64 rows: threads 0..63
    if (tid < 64) {
        float s = 0.f;
#pragma unroll
        for (int d0 = 0; d0 < 64; d0 += 8) {
            bf16x8 qv = *(const bf16x8*)&sQ[tid * 72 + d0];
#pragma unroll
            for (int jj = 0; jj < 8; jj++) s += (float)qv[jj] * ksst[d0 + jj];
        }
        den[tid] = s;
    }

    // ---- QK^T with causal masking. Wave w: rows w*16..+15 (local). Col frags cf=0..CFMAX.
    {
        int wr = w * 16;
        const int CFMAX = half ? (w + 4) : w;       // diag frag index
        const int CFLIM = half ? 7 : 3;
        const __bf16* kbase = kb + (size_t)(bh * 1024 + ch * 128) * 64;
        bf16x8 aq[2];
#pragma unroll
        for (int ks = 0; ks < 2; ks++)
            aq[ks] = *(const bf16x8*)&sQ[(wr + (l & 15)) * 72 + ks * 32 + ((l >> 4) << 3)];
        f32x4 acc[8] = {};
#pragma unroll
        for (int cf = 0; cf < 8; cf++) {
            if (cf <= CFMAX && cf <= CFLIM) {
#pragma unroll
                for (int ks = 0; ks < 2; ks++) {
                    bf16x8 bfr = *(const bf16x8*)&kbase[(size_t)(cf * 16 + (l & 15)) * 64 + ks * 32 + ((l >> 4) << 3)];
                    acc[cf] = MFMA16(aq[ks], bfr, acc[cf]);
                }
            }
        }
#pragma unroll
        for (int j = 0; j < 4; j++) {
            int lrow = wr + ((l >> 4) << 2) + j;
            int grow = half * 64 + lrow;            // row within chunk
            float rs = 0.f;
#pragma unroll
            for (int cf = 0; cf < 8; cf++) {
                if (cf <= CFMAX && cf <= CFLIM) {
                    int col = cf * 16 + (l & 15);
                    float v = acc[cf][j];
                    v = (col <= grow) ? v : 0.f;
                    rs += v;
                    sP[lrow * 136 + col] = (__bf16)v;
                }
            }
            if (CFMAX + 1 <= CFLIM) sP[lrow * 136 + (CFMAX + 1) * 16 + (l & 15)] = (__bf16)0.f;
#pragma unroll
            for (int off = 1; off < 16; off <<= 1) rs += __shfl_xor(rs, off);
            if ((l & 15) == 0) rsum[lrow] = rs;
        }
    }
    __syncthreads();

    // ---- O = P@V (ks <= ksmax) + Q@M (state). Wave w: rows w*16..+15, cols 0..63.
    f32x4 o[4] = {};
    {
        int wr = w * 16;
        int ksmax = half ? (2 + (w >> 1)) : (w >> 1);
        const __bf16* vbase = vtb + (size_t)bh * 65536 + ch * 128;
#pragma unroll
        for (int ks = 0; ks < 4; ks++) {
            if (ks <= ksmax) {
                bf16x8 a = *(const bf16x8*)&sP[(wr + (l & 15)) * 136 + ks * 32 + ((l >> 4) << 3)];
#pragma unroll
                for (int ni = 0; ni < 4; ni++) {
                    bf16x8 bfr = *(const bf16x8*)&vbase[(size_t)(ni * 16 + (l & 15)) * 1024 + ks * 32 + ((l >> 4) << 3)];
                    o[ni] = MFMA16(a, bfr, o[ni]);
                }
            }
        }
        if (ch > 0) {
#pragma unroll
            for (int ks = 0; ks < 2; ks++) {
                bf16x8 a = *(const bf16x8*)&sQ[(wr + (l & 15)) * 72 + ks * 32 + ((l >> 4) << 3)];
#pragma unroll
                for (int ni = 0; ni < 4; ni++) {
                    bf16x8 bfr = *(const bf16x8*)&sM[(ni * 16 + (l & 15)) * 72 + ks * 32 + ((l >> 4) << 3)];
                    o[ni] = MFMA16(a, bfr, o[ni]);
                }
            }
        }
    }

    // ---- epilogue
    __bf16* obase = attn_out + ((size_t)(b * 1024 + ch * 128 + half * 64)) * 512 + h * 64;
#pragma unroll
    for (int j = 0; j < 4; j++) {
        int lrow = w * 16 + ((l >> 4) << 2) + j;
        float dn = den[lrow] + rsum[lrow] + 1e-6f;
#pragma unroll
        for (int ni = 0; ni < 4; ni++) {
            int col = ni * 16 + (l & 15);
            obase[(size_t)lrow * 512 + col] = (__bf16)(o[ni][j] / dn);
        }
    }
}

// ---------------------------------------------------------------- fused proj + gate (128 blocks, 16 rows each)
// Phase A: pP = attn_tile @ woT + bo (fp32 in LDS). Phase B: g = sigmoid(pP@wg2T + xg + bg);
// out = x + g*(pP - x).
__global__ __launch_bounds__(256) void projgate_kernel(
    const __bf16* __restrict__ attn, const __bf16* __restrict__ woT,
    const __bf16* __restrict__ wg2T, const float* __restrict__ bo,
    const float* __restrict__ bg, const float* __restrict__ xg,
    const float* __restrict__ x, float* __restrict__ out) {
    __shared__ float pPf[16 * 516];
    int bm = blockIdx.x;
    int tid = threadIdx.x, w = tid >> 6, l = tid & 63;
    int gm0 = bm * 16;

    // phase A
    {
        f32x4 acc[8] = {};
        const __bf16* abase = attn + (size_t)gm0 * 512;
#pragma unroll
        for (int ks = 0; ks < 16; ks++) {
            bf16x8 a = *(const bf16x8*)&abase[(size_t)(l & 15) * 512 + ks * 32 + ((l >> 4) << 3)];
#pragma unroll
            for (int ni = 0; ni < 8; ni++) {
                bf16x8 bfr = *(const bf16x8*)&woT[(size_t)(w * 128 + ni * 16 + (l & 15)) * 512 + ks * 32 + ((l >> 4) << 3)];
                acc[ni] = MFMA16(a, bfr, acc[ni]);
            }
        }
#pragma unroll
        for (int ni = 0; ni < 8; ni++)
#pragma unroll
            for (int j = 0; j < 4; j++) {
                int row = ((l >> 4) << 2) + j;
                int col = w * 128 + ni * 16 + (l & 15);
                pPf[row * 516 + col] = acc[ni][j] + bo[col];
            }
    }
    __syncthreads();

    // phase B
    {
        f32x4 acc[8] = {};
#pragma unroll
        for (int ks = 0; ks < 16; ks++) {
            const float* pr = &pPf[(l & 15) * 516 + ks * 32 + ((l >> 4) << 3)];
            bf16x8 a;
#pragma unroll
            for (int j = 0; j < 8; j++) a[j] = (__bf16)pr[j];
#pragma unroll
            for (int ni = 0; ni < 8; ni++) {
                bf16x8 bfr = *(const bf16x8*)&wg2T[(size_t)(w * 128 + ni * 16 + (l & 15)) * 512 + ks * 32 + ((l >> 4) << 3)];
                acc[ni] = MFMA16(a, bfr, acc[ni]);
            }
        }
#pragma unroll
        for (int ni = 0; ni < 8; ni++)
#pragma unroll
            for (int j = 0; j < 4; j++) {
                int row = ((l >> 4) << 2) + j;
                int col = w * 128 + ni * 16 + (l & 15);
                int gm = gm0 + row;
                float gv = acc[ni][j] + xg[(size_t)gm * 512 + col] + bg[col];
                float g = 1.f / (1.f + __expf(-gv));
                float xv = x[(size_t)gm * 512 + col];
                float pv = pPf[row * 516 + col];
                out[(size_t)gm * 512 + col] = xv + g * (pv - xv);
            }
    }
}

// ----------------------------------------------------------------
extern "C" void kernel_launch(void* const* d_in, const int* in_sizes, int n_in,
                              void* d_out, int out_size, void* d_ws, size_t ws_size,
                              hipStream_t stream) {
    const float* x = (const float*)d_in[0];
    const float* Wq = (const float*)d_in[1];
    const float* Wk = (const float*)d_in[2];
    const float* Wv = (const float*)d_in[3];
    const float* Wo = (const float*)d_in[4];
    const float* bo = (const float*)d_in[5];
    const float* Wg = (const float*)d_in[6];
    const float* bg = (const float*)d_in[7];
    float* out = (float*)d_out;

    char* ws = (char*)d_ws;
    size_t off = 0;
    auto alloc = [&](size_t bytes) -> void* {
        void* p = ws + off;
        off += (bytes + 255) & ~(size_t)255;
        return p;
    };
    __bf16* xb     = (__bf16*)alloc((size_t)2048 * 512 * 2);
    __bf16* wqkvgT = (__bf16*)alloc((size_t)2048 * 512 * 2);
    __bf16* woT    = (__bf16*)alloc((size_t)512 * 512 * 2);
    __bf16* wg2T   = (__bf16*)alloc((size_t)512 * 512 * 2);
    __bf16* qb     = (__bf16*)alloc((size_t)16 * 1024 * 64 * 2);
    __bf16* kb     = (__bf16*)alloc((size_t)16 * 1024 * 64 * 2);
    __bf16* ktb    = (__bf16*)alloc((size_t)16 * 64 * 1024 * 2);
    __bf16* vtb    = (__bf16*)alloc((size_t)16 * 64 * 1024 * 2);
    float*  Mc     = (float*)alloc((size_t)128 * 4096 * 4);
    float*  ksc    = (float*)alloc((size_t)128 * 64 * 4);
    __bf16* attn   = (__bf16*)alloc((size_t)2048 * 512 * 2);
    float*  xg     = (float*)alloc((size_t)2048 * 512 * 4);

    prep_kernel<<<dim3(16, 32, 6), 256, 0, stream>>>(x, Wq, Wk, Wv, Wo, Wg, xb, wqkvgT, woT, wg2T);
    qkv_kernel<<<dim3(32, 16), 256, 0, stream>>>(xb, wqkvgT, qb, kb, ktb, vtb, xg);
    mc_kernel<<<128, 256, 0, stream>>>(ktb, vtb, Mc, ksc);
    attn_kernel<<<256, 256, 0, stream>>>(qb, kb, vtb, Mc, ksc, attn);
    projgate_kernel<<<128, 256, 0, stream>>>(attn, woT, wg2T, bo, bg, xg, x, out);
}

// Round 8
// 65.064 us; speedup vs baseline: 1.1765x; 1.1765x over previous
//
#include <hip/hip_runtime.h>
#include <hip/hip_bf16.h>
#include <math.h>

// B=2, S=1024, D=512, H=8, hd=64.  M = B*S = 2048.
// Chunked causal linear attention, chunk C=128, NC=8, BH=16.
// 6 launches: prep -> qkv GEMM -> mc -> attn(256) -> proj -> gate.
// GEMMs: 4-deep global_load_lds pipeline, counted vmcnt (T4), raw s_barrier.

typedef __bf16 bf16x8 __attribute__((ext_vector_type(8)));
typedef __bf16 bf16x4 __attribute__((ext_vector_type(4)));
typedef float f32x4 __attribute__((ext_vector_type(4)));

#define MFMA16(a, b, c) __builtin_amdgcn_mfma_f32_16x16x32_bf16(a, b, c, 0, 0, 0)

__device__ __forceinline__ float elu1(float v) { return v > 0.f ? v + 1.f : __expf(v); }

__device__ __forceinline__ void gload16(const void* g, void* l) {
    __builtin_amdgcn_global_load_lds((const __attribute__((address_space(1))) void*)g,
                                     (__attribute__((address_space(3))) void*)l, 16, 0, 0);
}

// ---------------------------------------------------------------- prep: x->bf16 + 5 weight transposes
__global__ __launch_bounds__(256) void prep_kernel(
    const float* __restrict__ x, const float* __restrict__ Wq, const float* __restrict__ Wk,
    const float* __restrict__ Wv, const float* __restrict__ Wo, const float* __restrict__ Wg,
    __bf16* __restrict__ xb, __bf16* __restrict__ wqkvT, __bf16* __restrict__ woT,
    __bf16* __restrict__ wgT) {
    int z = blockIdx.z;
    if (z == 5) {
        int bid = blockIdx.y * 16 + blockIdx.x;
        int base = (bid * 256 + threadIdx.x) * 8;
        bf16x8 o;
#pragma unroll
        for (int j = 0; j < 8; j++) o[j] = (__bf16)x[base + j];
        *(bf16x8*)&xb[base] = o;
        return;
    }
    const float* in;
    __bf16* out;
    int R = 512, C = 512;
    if (z == 0) { in = Wq; out = wqkvT; }
    else if (z == 1) { in = Wk; out = wqkvT + (size_t)512 * 512; }
    else if (z == 2) { in = Wv; out = wqkvT + (size_t)1024 * 512; }
    else if (z == 3) { in = Wo; out = woT; }
    else { in = Wg; out = wgT; R = 1024; }
    if ((int)blockIdx.y * 32 >= R) return;
    __shared__ float t[32][33];
    int bx = blockIdx.x, by = blockIdx.y;
    int tx = threadIdx.x & 31, ty = threadIdx.x >> 5;
#pragma unroll
    for (int i = 0; i < 32; i += 8)
        t[ty + i][tx] = in[(size_t)(by * 32 + ty + i) * C + bx * 32 + tx];
    __syncthreads();
#pragma unroll
    for (int i = 0; i < 32; i += 8)
        out[(size_t)(bx * 32 + ty + i) * R + by * 32 + tx] = (__bf16)t[tx][ty + i];
}

// ---------------------------------------------------------------- pipelined GEMM (BMxBN tile, BK=32, depth 4)
// A row-major [M][K] bf16 ; Bw row-major [N][K] bf16 (B^T) ; fp32 accum.
// MODE 0: qkv epilogue; MODE 1: proj epilogue; MODE 2: gate epilogue.
template <int MODE, int BM, int BN>
__global__ __launch_bounds__(256) void gemm_kernel(
    const __bf16* __restrict__ A, const __bf16* __restrict__ A2,
    const __bf16* __restrict__ Bw, const float* __restrict__ bias,
    const float* __restrict__ xf, const float* __restrict__ proj,
    float* __restrict__ outf, __bf16* __restrict__ outb,
    __bf16* __restrict__ q_out, __bf16* __restrict__ k_out,
    __bf16* __restrict__ kt_out, __bf16* __restrict__ vt_out, int K) {
    constexpr int MI = BM / 32, NI = BN / 32;
    constexpr int LA = BM / 64, LB = BN / 64;
    constexpr int L = LA + LB;  // gload16 per wave per stage
    __shared__ __bf16 sA[4 * BM * 32];
    __shared__ __bf16 sB[4 * BN * 32];
    int bm = blockIdx.x, bn = blockIdx.y;
    int tid = threadIdx.x, w = tid >> 6, l = tid & 63;
    int wr = (w >> 1) * (16 * MI), wc = (w & 1) * (16 * NI);
    int r = tid >> 2, c = (tid & 3) * 8;
    f32x4 acc[MI][NI] = {};
    const int nt = K / 32;

    auto stage = [&](int t, int buf) {
        int k0 = t * 32;
        const __bf16* a0 = A;
        int gka = k0, lda = K;
        if (MODE == 2) {
            lda = 512;
            if (k0 >= 512) { a0 = A2; gka = k0 - 512; }
        }
#pragma unroll
        for (int i = 0; i < LA; i++)
            gload16(&a0[(size_t)(bm * BM + i * 64 + r) * lda + gka + c],
                    &sA[buf * (BM * 32) + i * 2048 + w * 512]);
#pragma unroll
        for (int i = 0; i < LB; i++)
            gload16(&Bw[(size_t)(bn * BN + i * 64 + r) * K + k0 + c],
                    &sB[buf * (BN * 32) + i * 2048 + w * 512]);
    };

    stage(0, 0);
    stage(1, 1);
    stage(2, 2);
    for (int t = 0; t < nt; t++) {
        // ensure stage(t) complete; stages t+1, t+2 may stay in flight
        if (t + 2 < nt) {
            if constexpr (L == 2) asm volatile("s_waitcnt vmcnt(4)" ::: "memory");
            else asm volatile("s_waitcnt vmcnt(6)" ::: "memory");
        } else if (t + 1 < nt) {
            if constexpr (L == 2) asm volatile("s_waitcnt vmcnt(2)" ::: "memory");
            else asm volatile("s_waitcnt vmcnt(3)" ::: "memory");
        } else {
            asm volatile("s_waitcnt vmcnt(0)" ::: "memory");
        }
        asm volatile("s_barrier" ::: "memory");
        // buf (t+3)&3 was last read at iter t-1; all its ds_reads retired before this barrier
        if (t + 3 < nt) stage(t + 3, (t + 3) & 3);
        int buf = t & 3;
        bf16x8 af[MI], bfr[NI];
#pragma unroll
        for (int mi = 0; mi < MI; mi++)
            af[mi] = *(const bf16x8*)&sA[buf * (BM * 32) + (wr + mi * 16 + (l & 15)) * 32 + ((l >> 4) << 3)];
#pragma unroll
        for (int ni = 0; ni < NI; ni++)
            bfr[ni] = *(const bf16x8*)&sB[buf * (BN * 32) + (wc + ni * 16 + (l & 15)) * 32 + ((l >> 4) << 3)];
#pragma unroll
        for (int mi = 0; mi < MI; mi++)
#pragma unroll
            for (int ni = 0; ni < NI; ni++)
                acc[mi][ni] = MFMA16(af[mi], bfr[ni], acc[mi][ni]);
    }

    if (MODE == 0) {
#pragma unroll
        for (int mi = 0; mi < MI; mi++) {
            int gm0 = bm * BM + wr + mi * 16 + ((l >> 4) << 2);
            int b = gm0 >> 10, s0 = gm0 & 1023;
#pragma unroll
            for (int ni = 0; ni < NI; ni++) {
                int gn = bn * BN + wc + ni * 16 + (l & 15);
                int which = gn >> 9, h = (gn >> 6) & 7, d = gn & 63;
                int bh = b * 8 + h;
                if (which == 0) {
#pragma unroll
                    for (int j = 0; j < 4; j++)
                        q_out[((size_t)(bh * 1024 + s0 + j)) * 64 + d] = (__bf16)elu1(acc[mi][ni][j]);
                } else if (which == 1) {
                    bf16x4 pk;
#pragma unroll
                    for (int j = 0; j < 4; j++) {
                        __bf16 tb = (__bf16)elu1(acc[mi][ni][j]);
                        pk[j] = tb;
                        k_out[((size_t)(bh * 1024 + s0 + j)) * 64 + d] = tb;
                    }
                    *(bf16x4*)&kt_out[((size_t)(bh * 64 + d)) * 1024 + s0] = pk;
                } else {
                    bf16x4 pv;
#pragma unroll
                    for (int j = 0; j < 4; j++) pv[j] = (__bf16)acc[mi][ni][j];
                    *(bf16x4*)&vt_out[((size_t)(bh * 64 + d)) * 1024 + s0] = pv;
                }
            }
        }
    } else {
#pragma unroll
        for (int mi = 0; mi < MI; mi++)
#pragma unroll
            for (int ni = 0; ni < NI; ni++)
#pragma unroll
                for (int j = 0; j < 4; j++) {
                    int gm = bm * BM + wr + mi * 16 + ((l >> 4) << 2) + j;
                    int gn = bn * BN + wc + ni * 16 + (l & 15);
                    float v = acc[mi][ni][j] + bias[gn];
                    if (MODE == 1) {
                        outf[(size_t)gm * 512 + gn] = v;
                        outb[(size_t)gm * 512 + gn] = (__bf16)v;
                    } else {
                        float g = 1.f / (1.f + __expf(-v));
                        float xv = xf[(size_t)gm * 512 + gn];
                        float pv = proj[(size_t)gm * 512 + gn];
                        outf[(size_t)gm * 512 + gn] = xv + g * (pv - xv);
                    }
                }
    }
}

// ---------------------------------------------------------------- per-chunk M_c = V^T K + ksum_c (128 blocks)
__global__ __launch_bounds__(256) void mc_kernel(const __bf16* __restrict__ ktb,
                                                 const __bf16* __restrict__ vtb,
                                                 float* __restrict__ Mc, float* __restrict__ ksc) {
    int blk = blockIdx.x;
    int bh = blk >> 3, ch = blk & 7;
    int tid = threadIdx.x, w = tid >> 6, l = tid & 63;
    const __bf16* vb = vtb + (size_t)bh * 65536 + ch * 128;
    const __bf16* kp = ktb + (size_t)bh * 65536 + ch * 128;
    f32x4 macc[4] = {};
#pragma unroll
    for (int ks = 0; ks < 4; ks++) {
        bf16x8 a = *(const bf16x8*)&vb[(size_t)(w * 16 + (l & 15)) * 1024 + ks * 32 + ((l >> 4) << 3)];
#pragma unroll
        for (int ni = 0; ni < 4; ni++) {
            bf16x8 bb = *(const bf16x8*)&kp[(size_t)(ni * 16 + (l & 15)) * 1024 + ks * 32 + ((l >> 4) << 3)];
            macc[ni] = MFMA16(a, bb, macc[ni]);
        }
    }
    float* mout = Mc + (size_t)blk * 4096;
#pragma unroll
    for (int ni = 0; ni < 4; ni++)
#pragma unroll
        for (int j = 0; j < 4; j++)
            mout[(size_t)(w * 16 + ((l >> 4) << 2) + j) * 64 + ni * 16 + (l & 15)] = macc[ni][j];
    if (tid < 64) {
        float s = 0.f;
        const __bf16* kr = ktb + (size_t)(bh * 64 + tid) * 1024 + ch * 128;
#pragma unroll
        for (int t = 0; t < 16; t++) {
            bf16x8 v = *(const bf16x8*)&kr[t * 8];
#pragma unroll
            for (int j = 0; j < 8; j++) s += (float)v[j];
        }
        ksc[blk * 64 + tid] = s;
    }
}

// ---------------------------------------------------------------- attention: 256 blocks (bh, ch, half)
__global__ __launch_bounds__(256) void attn_kernel(
    const __bf16* __restrict__ qb, const __bf16* __restrict__ kb,
    const __bf16* __restrict__ vtb, const float* __restrict__ Mc,
    const float* __restrict__ ksc, __bf16* __restrict__ attn_out) {
    int blk = blockIdx.x;
    int bh = blk >> 4, ch = (blk >> 1) & 7, half = blk & 1;
    int b = bh >> 3, h = bh & 7;
    int tid = threadIdx.x, w = tid >> 6, l = tid & 63;

    __shared__ __bf16 sQ[64 * 72];
    __shared__ __bf16 sP[64 * 136];
    __shared__ __bf16 sM[64 * 72];
    __shared__ float den[64];
    __shared__ float rsum[64];
    __shared__ float ksst[64];

    const __bf16* qsrc = qb + (size_t)(bh * 1024 + ch * 128 + half * 64) * 64;
#pragma unroll
    for (int i = 0; i < 2; i++) {
        int e = i * 2048 + tid * 8;
        *(bf16x8*)&sQ[(e >> 6) * 72 + (e & 63)] = *(const bf16x8*)&qsrc[e];
    }
    {
        int r0 = tid >> 2, c0 = (tid & 3) * 16;
        f32x4 s0 = {}, s1 = {}, s2 = {}, s3 = {};
        const float* mcb = Mc + (size_t)(bh * 8) * 4096 + r0 * 64 + c0;
        for (int c = 0; c < ch; c++) {
            const float* p = mcb + (size_t)c * 4096;
            s0 += *(const f32x4*)&p[0];
            s1 += *(const f32x4*)&p[4];
            s2 += *(const f32x4*)&p[8];
            s3 += *(const f32x4*)&p[12];
        }
        __bf16* d = &sM[r0 * 72 + c0];
#pragma unroll
        for (int j = 0; j < 4; j++) {
            d[j] = (__bf16)s0[j];
            d[4 + j] = (__bf16)s1[j];
            d[8 + j] = (__bf16)s2[j];
            d[12 + j] = (__bf16)s3[j];
        }
    }
    if (tid < 64) {
        float s = 0.f;
        for (int c = 0; c < ch; c++) s += ksc[(bh * 8 + c) * 64 + tid];
        ksst[tid] = s;
    }
    __syncthreads();

    if (tid < 64) {
        float s = 0.f;
#pragma unroll
        for (int d0 = 0; d0 < 64; d0 += 8) {
            bf16x8 qv = *(const bf16x8*)&sQ[tid * 72 + d0];
#pragma unroll
            for (int jj = 0; jj < 8; jj++) s += (float)qv[jj] * ksst[d0 + jj];
        }
        den[tid] = s;
    }

    {
        int wr = w * 16;
        const int CFMAX = half ? (w + 4) : w;
        const int CFLIM = half ? 7 : 3;
        const __bf16* kbase = kb + (size_t)(bh * 1024 + ch * 128) * 64;
        bf16x8 aq[2];
#pragma unroll
        for (int ks = 0; ks < 2; ks++)
            aq[ks] = *(const bf16x8*)&sQ[(wr + (l & 15)) * 72 + ks * 32 + ((l >> 4) << 3)];
        f32x4 acc[8] = {};
#pragma unroll
        for (int cf = 0; cf < 8; cf++) {
            if (cf <= CFMAX && cf <= CFLIM) {
#pragma unroll
                for (int ks = 0; ks < 2; ks++) {
                    bf16x8 bfr = *(const bf16x8*)&kbase[(size_t)(cf * 16 + (l & 15)) * 64 + ks * 32 + ((l >> 4) << 3)];
                    acc[cf] = MFMA16(aq[ks], bfr, acc[cf]);
                }
            }
        }
#pragma unroll
        for (int j = 0; j < 4; j++) {
            int lrow = wr + ((l >> 4) << 2) + j;
            int grow = half * 64 + lrow;
            float rs = 0.f;
#pragma unroll
            for (int cf = 0; cf < 8; cf++) {
                if (cf <= CFMAX && cf <= CFLIM) {
                    int col = cf * 16 + (l & 15);
                    float v = acc[cf][j];
                    v = (col <= grow) ? v : 0.f;
                    rs += v;
                    sP[lrow * 136 + col] = (__bf16)v;
                }
            }
            if (CFMAX + 1 <= CFLIM) sP[lrow * 136 + (CFMAX + 1) * 16 + (l & 15)] = (__bf16)0.f;
#pragma unroll
            for (int off = 1; off < 16; off <<= 1) rs += __shfl_xor(rs, off);
            if ((l & 15) == 0) rsum[lrow] = rs;
        }
    }
    __syncthreads();

    f32x4 o[4] = {};
    {
        int wr = w * 16;
        int ksmax = half ? (2 + (w >> 1)) : (w >> 1);
        const __bf16* vbase = vtb + (size_t)bh * 65536 + ch * 128;
#pragma unroll
        for (int ks = 0; ks < 4; ks++) {
            if (ks <= ksmax) {
                bf16x8 a = *(const bf16x8*)&sP[(wr + (l & 15)) * 136 + ks * 32 + ((l >> 4) << 3)];
#pragma unroll
                for (int ni = 0; ni < 4; ni++) {
                    bf16x8 bfr = *(const bf16x8*)&vbase[(size_t)(ni * 16 + (l & 15)) * 1024 + ks * 32 + ((l >> 4) << 3)];
                    o[ni] = MFMA16(a, bfr, o[ni]);
                }
            }
        }
        if (ch > 0) {
#pragma unroll
            for (int ks = 0; ks < 2; ks++) {
                bf16x8 a = *(const bf16x8*)&sQ[(wr + (l & 15)) * 72 + ks * 32 + ((l >> 4) << 3)];
#pragma unroll
                for (int ni = 0; ni < 4; ni++) {
                    bf16x8 bfr = *(const bf16x8*)&sM[(ni * 16 + (l & 15)) * 72 + ks * 32 + ((l >> 4) << 3)];
                    o[ni] = MFMA16(a, bfr, o[ni]);
                }
            }
        }
    }

    __bf16* obase = attn_out + ((size_t)(b * 1024 + ch * 128 + half * 64)) * 512 + h * 64;
#pragma unroll
    for (int j = 0; j < 4; j++) {
        int lrow = w * 16 + ((l >> 4) << 2) + j;
        float dn = den[lrow] + rsum[lrow] + 1e-6f;
#pragma unroll
        for (int ni = 0; ni < 4; ni++) {
            int col = ni * 16 + (l & 15);
            obase[(size_t)lrow * 512 + col] = (__bf16)(o[ni][j] / dn);
        }
    }
}

// ----------------------------------------------------------------
extern "C" void kernel_launch(void* const* d_in, const int* in_sizes, int n_in,
                              void* d_out, int out_size, void* d_ws, size_t ws_size,
                              hipStream_t stream) {
    const float* x = (const float*)d_in[0];
    const float* Wq = (const float*)d_in[1];
    const float* Wk = (const float*)d_in[2];
    const float* Wv = (const float*)d_in[3];
    const float* Wo = (const float*)d_in[4];
    const float* bo = (const float*)d_in[5];
    const float* Wg = (const float*)d_in[6];
    const float* bg = (const float*)d_in[7];
    float* out = (float*)d_out;

    char* ws = (char*)d_ws;
    size_t off = 0;
    auto alloc = [&](size_t bytes) -> void* {
        void* p = ws + off;
        off += (bytes + 255) & ~(size_t)255;
        return p;
    };
    __bf16* xb    = (__bf16*)alloc((size_t)2048 * 512 * 2);
    __bf16* wqkvT = (__bf16*)alloc((size_t)1536 * 512 * 2);
    __bf16* woT   = (__bf16*)alloc((size_t)512 * 512 * 2);
    __bf16* wgT   = (__bf16*)alloc((size_t)512 * 1024 * 2);
    __bf16* qb    = (__bf16*)alloc((size_t)16 * 1024 * 64 * 2);
    __bf16* kb    = (__bf16*)alloc((size_t)16 * 1024 * 64 * 2);
    __bf16* ktb   = (__bf16*)alloc((size_t)16 * 64 * 1024 * 2);
    __bf16* vtb   = (__bf16*)alloc((size_t)16 * 64 * 1024 * 2);
    float*  Mc    = (float*)alloc((size_t)128 * 4096 * 4);
    float*  ksc   = (float*)alloc((size_t)128 * 64 * 4);
    __bf16* attn  = (__bf16*)alloc((size_t)2048 * 512 * 2);
    float*  proj  = (float*)alloc((size_t)2048 * 512 * 4);
    __bf16* projb = (__bf16*)alloc((size_t)2048 * 512 * 2);

    prep_kernel<<<dim3(16, 32, 6), 256, 0, stream>>>(x, Wq, Wk, Wv, Wo, Wg, xb, wqkvT, woT, wgT);
    gemm_kernel<0, 64, 128><<<dim3(32, 12), 256, 0, stream>>>(
        xb, nullptr, wqkvT, nullptr, nullptr, nullptr, nullptr, nullptr, qb, kb, ktb, vtb, 512);
    mc_kernel<<<128, 256, 0, stream>>>(ktb, vtb, Mc, ksc);
    attn_kernel<<<256, 256, 0, stream>>>(qb, kb, vtb, Mc, ksc, attn);
    gemm_kernel<1, 64, 64><<<dim3(32, 8), 256, 0, stream>>>(
        attn, nullptr, woT, bo, nullptr, nullptr, proj, projb, nullptr, nullptr, nullptr, nullptr, 512);
    gemm_kernel<2, 64, 64><<<dim3(32, 8), 256, 0, stream>>>(
        xb, projb, wgT, bg, x, proj, out, nullptr, nullptr, nullptr, nullptr, nullptr, 1024);
}

// Round 9
// 64.328 us; speedup vs baseline: 1.1900x; 1.0114x over previous
//
#include <hip/hip_runtime.h>
#include <hip/hip_bf16.h>
#include <math.h>

// B=2, S=1024, D=512, H=8, hd=64.  M = B*S = 2048.
// Chunked causal linear attention, chunk C=128, NC=8, BH=16.
// 6 launches: prep -> qkv GEMM (64x64, 768 blks, LDS epilogue) -> mc -> attn(256) -> proj -> gate.

typedef __bf16 bf16x8 __attribute__((ext_vector_type(8)));
typedef __bf16 bf16x4 __attribute__((ext_vector_type(4)));
typedef float f32x4 __attribute__((ext_vector_type(4)));

#define MFMA16(a, b, c) __builtin_amdgcn_mfma_f32_16x16x32_bf16(a, b, c, 0, 0, 0)

__device__ __forceinline__ float elu1(float v) { return v > 0.f ? v + 1.f : __expf(v); }

__device__ __forceinline__ void gload16(const void* g, void* l) {
    __builtin_amdgcn_global_load_lds((const __attribute__((address_space(1))) void*)g,
                                     (__attribute__((address_space(3))) void*)l, 16, 0, 0);
}

// ---------------------------------------------------------------- prep: x->bf16 + 5 weight transposes
__global__ __launch_bounds__(256) void prep_kernel(
    const float* __restrict__ x, const float* __restrict__ Wq, const float* __restrict__ Wk,
    const float* __restrict__ Wv, const float* __restrict__ Wo, const float* __restrict__ Wg,
    __bf16* __restrict__ xb, __bf16* __restrict__ wqkvT, __bf16* __restrict__ woT,
    __bf16* __restrict__ wgT) {
    int z = blockIdx.z;
    if (z == 5) {
        int bid = blockIdx.y * 16 + blockIdx.x;
        int base = (bid * 256 + threadIdx.x) * 8;
        bf16x8 o;
#pragma unroll
        for (int j = 0; j < 8; j++) o[j] = (__bf16)x[base + j];
        *(bf16x8*)&xb[base] = o;
        return;
    }
    const float* in;
    __bf16* out;
    int R = 512, C = 512;
    if (z == 0) { in = Wq; out = wqkvT; }
    else if (z == 1) { in = Wk; out = wqkvT + (size_t)512 * 512; }
    else if (z == 2) { in = Wv; out = wqkvT + (size_t)1024 * 512; }
    else if (z == 3) { in = Wo; out = woT; }
    else { in = Wg; out = wgT; R = 1024; }
    if ((int)blockIdx.y * 32 >= R) return;
    __shared__ float t[32][33];
    int bx = blockIdx.x, by = blockIdx.y;
    int tx = threadIdx.x & 31, ty = threadIdx.x >> 5;
#pragma unroll
    for (int i = 0; i < 32; i += 8)
        t[ty + i][tx] = in[(size_t)(by * 32 + ty + i) * C + bx * 32 + tx];
    __syncthreads();
#pragma unroll
    for (int i = 0; i < 32; i += 8)
        out[(size_t)(bx * 32 + ty + i) * R + by * 32 + tx] = (__bf16)t[tx][ty + i];
}

// ---------------------------------------------------------------- pipelined GEMM (BMxBN tile, BK=32, depth 4)
// A row-major [M][K] bf16 ; Bw row-major [N][K] bf16 (B^T) ; fp32 accum.
// MODE 0: qkv epilogue (through-LDS coalesced stores); MODE 1: proj; MODE 2: gate.
template <int MODE, int BM, int BN>
__global__ __launch_bounds__(256) void gemm_kernel(
    const __bf16* __restrict__ A, const __bf16* __restrict__ A2,
    const __bf16* __restrict__ Bw, const float* __restrict__ bias,
    const float* __restrict__ xf, const float* __restrict__ proj,
    float* __restrict__ outf, __bf16* __restrict__ outb,
    __bf16* __restrict__ q_out, __bf16* __restrict__ k_out,
    __bf16* __restrict__ kt_out, __bf16* __restrict__ vt_out, int K) {
    constexpr int MI = BM / 32, NI = BN / 32;
    constexpr int LA = BM / 64, LB = BN / 64;
    constexpr int L = LA + LB;  // gload16 per wave per stage
    __shared__ __bf16 sA[4 * BM * 32];
    __shared__ __bf16 sB[4 * BN * 32];
    __shared__ __bf16 sE[(MODE == 0) ? 64 * 72 : 1];
    int bm = blockIdx.x, bn = blockIdx.y;
    int tid = threadIdx.x, w = tid >> 6, l = tid & 63;
    int wr = (w >> 1) * (16 * MI), wc = (w & 1) * (16 * NI);
    int r = tid >> 2, c = (tid & 3) * 8;
    f32x4 acc[MI][NI] = {};
    const int nt = K / 32;

    auto stage = [&](int t, int buf) {
        int k0 = t * 32;
        const __bf16* a0 = A;
        int gka = k0, lda = K;
        if (MODE == 2) {
            lda = 512;
            if (k0 >= 512) { a0 = A2; gka = k0 - 512; }
        }
#pragma unroll
        for (int i = 0; i < LA; i++)
            gload16(&a0[(size_t)(bm * BM + i * 64 + r) * lda + gka + c],
                    &sA[buf * (BM * 32) + i * 2048 + w * 512]);
#pragma unroll
        for (int i = 0; i < LB; i++)
            gload16(&Bw[(size_t)(bn * BN + i * 64 + r) * K + k0 + c],
                    &sB[buf * (BN * 32) + i * 2048 + w * 512]);
    };

    stage(0, 0);
    stage(1, 1);
    stage(2, 2);
    for (int t = 0; t < nt; t++) {
        if (t + 2 < nt) {
            if constexpr (L == 2) asm volatile("s_waitcnt vmcnt(4)" ::: "memory");
            else asm volatile("s_waitcnt vmcnt(6)" ::: "memory");
        } else if (t + 1 < nt) {
            if constexpr (L == 2) asm volatile("s_waitcnt vmcnt(2)" ::: "memory");
            else asm volatile("s_waitcnt vmcnt(3)" ::: "memory");
        } else {
            asm volatile("s_waitcnt vmcnt(0)" ::: "memory");
        }
        asm volatile("s_barrier" ::: "memory");
        if (t + 3 < nt) stage(t + 3, (t + 3) & 3);
        int buf = t & 3;
        bf16x8 af[MI], bfr[NI];
#pragma unroll
        for (int mi = 0; mi < MI; mi++)
            af[mi] = *(const bf16x8*)&sA[buf * (BM * 32) + (wr + mi * 16 + (l & 15)) * 32 + ((l >> 4) << 3)];
#pragma unroll
        for (int ni = 0; ni < NI; ni++)
            bfr[ni] = *(const bf16x8*)&sB[buf * (BN * 32) + (wc + ni * 16 + (l & 15)) * 32 + ((l >> 4) << 3)];
#pragma unroll
        for (int mi = 0; mi < MI; mi++)
#pragma unroll
            for (int ni = 0; ni < NI; ni++)
                acc[mi][ni] = MFMA16(af[mi], bfr[ni], acc[mi][ni]);
    }

    if (MODE == 0) {
        // qkv epilogue: fragments -> sE (activation applied) -> coalesced 16B stores.
        __syncthreads();
#pragma unroll
        for (int mi = 0; mi < MI; mi++)
#pragma unroll
            for (int ni = 0; ni < NI; ni++)
#pragma unroll
                for (int j = 0; j < 4; j++) {
                    int lr = wr + mi * 16 + ((l >> 4) << 2) + j;
                    int lc = wc + ni * 16 + (l & 15);
                    float v = acc[mi][ni][j];
                    if (bn < 16) v = elu1(v);  // q,k sections get feature map
                    sE[lr * 72 + lc] = (__bf16)v;
                }
        __syncthreads();
        int which = bn >> 3;  // bn 0-7: q, 8-15: k, 16-23: v
        int b = bm >> 4, s0b = (bm & 15) * 64, h = bn & 7;
        int bh = b * 8 + h;
        if (which == 0 || which == 1) {
            // token-major [s][d], contiguous 8KB region
            __bf16* qk = (which == 0 ? q_out : k_out) + ((size_t)(bh * 1024 + s0b)) * 64;
#pragma unroll
            for (int p = 0; p < 2; p++) {
                int idx = p * 256 + tid;
                *(bf16x8*)&qk[idx * 8] = *(const bf16x8*)&sE[(idx >> 3) * 72 + (idx & 7) * 8];
            }
        }
        if (which >= 1) {
            // feature-major [d][s]: lane = d, wave = s-group (conflict-free LDS rows)
            __bf16* tdst = (which == 1 ? kt_out : vt_out) + (size_t)(bh * 64) * 1024 + s0b;
            alignas(16) __bf16 tmp[16];
#pragma unroll
            for (int sj = 0; sj < 16; sj++) tmp[sj] = sE[(w * 16 + sj) * 72 + l];
            *(bf16x8*)&tdst[(size_t)l * 1024 + w * 16] = *(const bf16x8*)&tmp[0];
            *(bf16x8*)&tdst[(size_t)l * 1024 + w * 16 + 8] = *(const bf16x8*)&tmp[8];
        }
    } else {
#pragma unroll
        for (int mi = 0; mi < MI; mi++)
#pragma unroll
            for (int ni = 0; ni < NI; ni++)
#pragma unroll
                for (int j = 0; j < 4; j++) {
                    int gm = bm * BM + wr + mi * 16 + ((l >> 4) << 2) + j;
                    int gn = bn * BN + wc + ni * 16 + (l & 15);
                    float v = acc[mi][ni][j] + bias[gn];
                    if (MODE == 1) {
                        outf[(size_t)gm * 512 + gn] = v;
                        outb[(size_t)gm * 512 + gn] = (__bf16)v;
                    } else {
                        float g = 1.f / (1.f + __expf(-v));
                        float xv = xf[(size_t)gm * 512 + gn];
                        float pv = proj[(size_t)gm * 512 + gn];
                        outf[(size_t)gm * 512 + gn] = xv + g * (pv - xv);
                    }
                }
    }
}

// ---------------------------------------------------------------- per-chunk M_c = V^T K + ksum_c (128 blocks)
__global__ __launch_bounds__(256) void mc_kernel(const __bf16* __restrict__ ktb,
                                                 const __bf16* __restrict__ vtb,
                                                 float* __restrict__ Mc, float* __restrict__ ksc) {
    int blk = blockIdx.x;
    int bh = blk >> 3, ch = blk & 7;
    int tid = threadIdx.x, w = tid >> 6, l = tid & 63;
    const __bf16* vb = vtb + (size_t)bh * 65536 + ch * 128;
    const __bf16* kp = ktb + (size_t)bh * 65536 + ch * 128;
    f32x4 macc[4] = {};
#pragma unroll
    for (int ks = 0; ks < 4; ks++) {
        bf16x8 a = *(const bf16x8*)&vb[(size_t)(w * 16 + (l & 15)) * 1024 + ks * 32 + ((l >> 4) << 3)];
#pragma unroll
        for (int ni = 0; ni < 4; ni++) {
            bf16x8 bb = *(const bf16x8*)&kp[(size_t)(ni * 16 + (l & 15)) * 1024 + ks * 32 + ((l >> 4) << 3)];
            macc[ni] = MFMA16(a, bb, macc[ni]);
        }
    }
    float* mout = Mc + (size_t)blk * 4096;
#pragma unroll
    for (int ni = 0; ni < 4; ni++)
#pragma unroll
        for (int j = 0; j < 4; j++)
            mout[(size_t)(w * 16 + ((l >> 4) << 2) + j) * 64 + ni * 16 + (l & 15)] = macc[ni][j];
    if (tid < 64) {
        float s = 0.f;
        const __bf16* kr = ktb + (size_t)(bh * 64 + tid) * 1024 + ch * 128;
#pragma unroll
        for (int t = 0; t < 16; t++) {
            bf16x8 v = *(const bf16x8*)&kr[t * 8];
#pragma unroll
            for (int j = 0; j < 8; j++) s += (float)v[j];
        }
        ksc[blk * 64 + tid] = s;
    }
}

// ---------------------------------------------------------------- attention: 256 blocks (bh, ch, half)
__global__ __launch_bounds__(256) void attn_kernel(
    const __bf16* __restrict__ qb, const __bf16* __restrict__ kb,
    const __bf16* __restrict__ vtb, const float* __restrict__ Mc,
    const float* __restrict__ ksc, __bf16* __restrict__ attn_out) {
    int blk = blockIdx.x;
    int bh = blk >> 4, ch = (blk >> 1) & 7, half = blk & 1;
    int b = bh >> 3, h = bh & 7;
    int tid = threadIdx.x, w = tid >> 6, l = tid & 63;

    __shared__ __bf16 sQ[64 * 72];
    __shared__ __bf16 sP[64 * 136];
    __shared__ __bf16 sM[64 * 72];
    __shared__ float den[64];
    __shared__ float rsum[64];
    __shared__ float ksst[64];

    const __bf16* qsrc = qb + (size_t)(bh * 1024 + ch * 128 + half * 64) * 64;
#pragma unroll
    for (int i = 0; i < 2; i++) {
        int e = i * 2048 + tid * 8;
        *(bf16x8*)&sQ[(e >> 6) * 72 + (e & 63)] = *(const bf16x8*)&qsrc[e];
    }
    {
        int r0 = tid >> 2, c0 = (tid & 3) * 16;
        f32x4 s0 = {}, s1 = {}, s2 = {}, s3 = {};
        const float* mcb = Mc + (size_t)(bh * 8) * 4096 + r0 * 64 + c0;
        for (int c = 0; c < ch; c++) {
            const float* p = mcb + (size_t)c * 4096;
            s0 += *(const f32x4*)&p[0];
            s1 += *(const f32x4*)&p[4];
            s2 += *(const f32x4*)&p[8];
            s3 += *(const f32x4*)&p[12];
        }
        __bf16* d = &sM[r0 * 72 + c0];
#pragma unroll
        for (int j = 0; j < 4; j++) {
            d[j] = (__bf16)s0[j];
            d[4 + j] = (__bf16)s1[j];
            d[8 + j] = (__bf16)s2[j];
            d[12 + j] = (__bf16)s3[j];
        }
    }
    if (tid < 64) {
        float s = 0.f;
        for (int c = 0; c < ch; c++) s += ksc[(bh * 8 + c) * 64 + tid];
        ksst[tid] = s;
    }
    __syncthreads();

    if (tid < 64) {
        float s = 0.f;
#pragma unroll
        for (int d0 = 0; d0 < 64; d0 += 8) {
            bf16x8 qv = *(const bf16x8*)&sQ[tid * 72 + d0];
#pragma unroll
            for (int jj = 0; jj < 8; jj++) s += (float)qv[jj] * ksst[d0 + jj];
        }
        den[tid] = s;
    }

    {
        int wr = w * 16;
        const int CFMAX = half ? (w + 4) : w;
        const int CFLIM = half ? 7 : 3;
        const __bf16* kbase = kb + (size_t)(bh * 1024 + ch * 128) * 64;
        bf16x8 aq[2];
#pragma unroll
        for (int ks = 0; ks < 2; ks++)
            aq[ks] = *(const bf16x8*)&sQ[(wr + (l & 15)) * 72 + ks * 32 + ((l >> 4) << 3)];
        f32x4 acc[8] = {};
#pragma unroll
        for (int cf = 0; cf < 8; cf++) {
            if (cf <= CFMAX && cf <= CFLIM) {
#pragma unroll
                for (int ks = 0; ks < 2; ks++) {
                    bf16x8 bfr = *(const bf16x8*)&kbase[(size_t)(cf * 16 + (l & 15)) * 64 + ks * 32 + ((l >> 4) << 3)];
                    acc[cf] = MFMA16(aq[ks], bfr, acc[cf]);
                }
            }
        }
#pragma unroll
        for (int j = 0; j < 4; j++) {
            int lrow = wr + ((l >> 4) << 2) + j;
            int grow = half * 64 + lrow;
            float rs = 0.f;
#pragma unroll
            for (int cf = 0; cf < 8; cf++) {
                if (cf <= CFMAX && cf <= CFLIM) {
                    int col = cf * 16 + (l & 15);
                    float v = acc[cf][j];
                    v = (col <= grow) ? v : 0.f;
                    rs += v;
                    sP[lrow * 136 + col] = (__bf16)v;
                }
            }
            if (CFMAX + 1 <= CFLIM) sP[lrow * 136 + (CFMAX + 1) * 16 + (l & 15)] = (__bf16)0.f;
#pragma unroll
            for (int off = 1; off < 16; off <<= 1) rs += __shfl_xor(rs, off);
            if ((l & 15) == 0) rsum[lrow] = rs;
        }
    }
    __syncthreads();

    f32x4 o[4] = {};
    {
        int wr = w * 16;
        int ksmax = half ? (2 + (w >> 1)) : (w >> 1);
        const __bf16* vbase = vtb + (size_t)bh * 65536 + ch * 128;
#pragma unroll
        for (int ks = 0; ks < 4; ks++) {
            if (ks <= ksmax) {
                bf16x8 a = *(const bf16x8*)&sP[(wr + (l & 15)) * 136 + ks * 32 + ((l >> 4) << 3)];
#pragma unroll
                for (int ni = 0; ni < 4; ni++) {
                    bf16x8 bfr = *(const bf16x8*)&vbase[(size_t)(ni * 16 + (l & 15)) * 1024 + ks * 32 + ((l >> 4) << 3)];
                    o[ni] = MFMA16(a, bfr, o[ni]);
                }
            }
        }
        if (ch > 0) {
#pragma unroll
            for (int ks = 0; ks < 2; ks++) {
                bf16x8 a = *(const bf16x8*)&sQ[(wr + (l & 15)) * 72 + ks * 32 + ((l >> 4) << 3)];
#pragma unroll
                for (int ni = 0; ni < 4; ni++) {
                    bf16x8 bfr = *(const bf16x8*)&sM[(ni * 16 + (l & 15)) * 72 + ks * 32 + ((l >> 4) << 3)];
                    o[ni] = MFMA16(a, bfr, o[ni]);
                }
            }
        }
    }

    __bf16* obase = attn_out + ((size_t)(b * 1024 + ch * 128 + half * 64)) * 512 + h * 64;
#pragma unroll
    for (int j = 0; j < 4; j++) {
        int lrow = w * 16 + ((l >> 4) << 2) + j;
        float dn = den[lrow] + rsum[lrow] + 1e-6f;
#pragma unroll
        for (int ni = 0; ni < 4; ni++) {
            int col = ni * 16 + (l & 15);
            obase[(size_t)lrow * 512 + col] = (__bf16)(o[ni][j] / dn);
        }
    }
}

// ----------------------------------------------------------------
extern "C" void kernel_launch(void* const* d_in, const int* in_sizes, int n_in,
                              void* d_out, int out_size, void* d_ws, size_t ws_size,
                              hipStream_t stream) {
    const float* x = (const float*)d_in[0];
    const float* Wq = (const float*)d_in[1];
    const float* Wk = (const float*)d_in[2];
    const float* Wv = (const float*)d_in[3];
    const float* Wo = (const float*)d_in[4];
    const float* bo = (const float*)d_in[5];
    const float* Wg = (const float*)d_in[6];
    const float* bg = (const float*)d_in[7];
    float* out = (float*)d_out;

    char* ws = (char*)d_ws;
    size_t off = 0;
    auto alloc = [&](size_t bytes) -> void* {
        void* p = ws + off;
        off += (bytes + 255) & ~(size_t)255;
        return p;
    };
    __bf16* xb    = (__bf16*)alloc((size_t)2048 * 512 * 2);
    __bf16* wqkvT = (__bf16*)alloc((size_t)1536 * 512 * 2);
    __bf16* woT   = (__bf16*)alloc((size_t)512 * 512 * 2);
    __bf16* wgT   = (__bf16*)alloc((size_t)512 * 1024 * 2);
    __bf16* qb    = (__bf16*)alloc((size_t)16 * 1024 * 64 * 2);
    __bf16* kb    = (__bf16*)alloc((size_t)16 * 1024 * 64 * 2);
    __bf16* ktb   = (__bf16*)alloc((size_t)16 * 64 * 1024 * 2);
    __bf16* vtb   = (__bf16*)alloc((size_t)16 * 64 * 1024 * 2);
    float*  Mc    = (float*)alloc((size_t)128 * 4096 * 4);
    float*  ksc   = (float*)alloc((size_t)128 * 64 * 4);
    __bf16* attn  = (__bf16*)alloc((size_t)2048 * 512 * 2);
    float*  proj  = (float*)alloc((size_t)2048 * 512 * 4);
    __bf16* projb = (__bf16*)alloc((size_t)2048 * 512 * 2);

    prep_kernel<<<dim3(16, 32, 6), 256, 0, stream>>>(x, Wq, Wk, Wv, Wo, Wg, xb, wqkvT, woT, wgT);
    gemm_kernel<0, 64, 64><<<dim3(32, 24), 256, 0, stream>>>(
        xb, nullptr, wqkvT, nullptr, nullptr, nullptr, nullptr, nullptr, qb, kb, ktb, vtb, 512);
    mc_kernel<<<128, 256, 0, stream>>>(ktb, vtb, Mc, ksc);
    attn_kernel<<<256, 256, 0, stream>>>(qb, kb, vtb, Mc, ksc, attn);
    gemm_kernel<1, 64, 64><<<dim3(32, 8), 256, 0, stream>>>(
        attn, nullptr, woT, bo, nullptr, nullptr, proj, projb, nullptr, nullptr, nullptr, nullptr, 512);
    gemm_kernel<2, 64, 64><<<dim3(32, 8), 256, 0, stream>>>(
        xb, projb, wgT, bg, x, proj, out, nullptr, nullptr, nullptr, nullptr, nullptr, 1024);
}

// Round 10
// 62.975 us; speedup vs baseline: 1.2155x; 1.0215x over previous
//
#include <hip/hip_runtime.h>
#include <hip/hip_bf16.h>
#include <math.h>

// B=2, S=1024, D=512, H=8, hd=64.  M = B*S = 2048.
// Chunked causal linear attention, chunk C=128, NC=8, BH=16.
// 6 launches: prep -> qkv+xg GEMM (N=2048) -> mc -> attn(256) -> proj(bf16 out) -> gate(K=512).

typedef __bf16 bf16x8 __attribute__((ext_vector_type(8)));
typedef __bf16 bf16x4 __attribute__((ext_vector_type(4)));
typedef float f32x4 __attribute__((ext_vector_type(4)));

#define MFMA16(a, b, c) __builtin_amdgcn_mfma_f32_16x16x32_bf16(a, b, c, 0, 0, 0)

__device__ __forceinline__ float elu1(float v) { return v > 0.f ? v + 1.f : __expf(v); }

__device__ __forceinline__ void gload16(const void* g, void* l) {
    __builtin_amdgcn_global_load_lds((const __attribute__((address_space(1))) void*)g,
                                     (__attribute__((address_space(3))) void*)l, 16, 0, 0);
}

// ---------------------------------------------------------------- prep: x->bf16 + weight transposes
// z=0..2 -> wqkvT rows 0..1535 {Wq,Wk,Wv}; z=3 -> woT; z=4 -> Wg split: k<512 -> wqkvT rows 1536..2047,
// k>=512 -> wg2T; z=5 -> x conversion.
__global__ __launch_bounds__(256) void prep_kernel(
    const float* __restrict__ x, const float* __restrict__ Wq, const float* __restrict__ Wk,
    const float* __restrict__ Wv, const float* __restrict__ Wo, const float* __restrict__ Wg,
    __bf16* __restrict__ xb, __bf16* __restrict__ wqkvT, __bf16* __restrict__ woT,
    __bf16* __restrict__ wg2T) {
    int z = blockIdx.z;
    if (z == 5) {
        int bid = blockIdx.y * 16 + blockIdx.x;
        int base = (bid * 256 + threadIdx.x) * 8;
        bf16x8 o;
#pragma unroll
        for (int j = 0; j < 8; j++) o[j] = (__bf16)x[base + j];
        *(bf16x8*)&xb[base] = o;
        return;
    }
    const float* in;
    int R = 512;
    if (z == 0) in = Wq;
    else if (z == 1) in = Wk;
    else if (z == 2) in = Wv;
    else if (z == 3) in = Wo;
    else { in = Wg; R = 1024; }
    if ((int)blockIdx.y * 32 >= R) return;
    __shared__ float t[32][33];
    int bx = blockIdx.x, by = blockIdx.y;
    int tx = threadIdx.x & 31, ty = threadIdx.x >> 5;
#pragma unroll
    for (int i = 0; i < 32; i += 8)
        t[ty + i][tx] = in[(size_t)(by * 32 + ty + i) * 512 + bx * 32 + tx];
    __syncthreads();
#pragma unroll
    for (int i = 0; i < 32; i += 8) {
        int n = bx * 32 + ty + i;   // output row (col of W)
        int kk = by * 32 + tx;      // output col (row of W)
        __bf16 val = (__bf16)t[tx][ty + i];
        if (z == 0) wqkvT[(size_t)n * 512 + kk] = val;
        else if (z == 1) wqkvT[(size_t)(512 + n) * 512 + kk] = val;
        else if (z == 2) wqkvT[(size_t)(1024 + n) * 512 + kk] = val;
        else if (z == 3) woT[(size_t)n * 512 + kk] = val;
        else if (kk < 512) wqkvT[(size_t)(1536 + n) * 512 + kk] = val;
        else wg2T[(size_t)n * 512 + (kk - 512)] = val;
    }
}

// ---------------------------------------------------------------- pipelined GEMM (BMxBN, BK=32, depth 4)
// A row-major [M][K] bf16 ; Bw row-major [N][K] bf16 (B^T) ; fp32 accum.
// MODE 0: qkv+xg epilogue (LDS-coalesced); MODE 1: proj -> bf16; MODE 2: gate (+xg, sigmoid, mix).
template <int MODE, int BM, int BN>
__global__ __launch_bounds__(256) void gemm_kernel(
    const __bf16* __restrict__ A, const __bf16* __restrict__ Bw, const float* __restrict__ bias,
    const float* __restrict__ xf, const __bf16* __restrict__ xgb, const __bf16* __restrict__ pvb,
    float* __restrict__ outf, __bf16* __restrict__ outb,
    __bf16* __restrict__ q_out, __bf16* __restrict__ k_out,
    __bf16* __restrict__ kt_out, __bf16* __restrict__ vt_out, __bf16* __restrict__ xg_out, int K) {
    constexpr int MI = BM / 32, NI = BN / 32;
    constexpr int LA = BM / 64, LB = BN / 64;
    constexpr int L = LA + LB;
    __shared__ __bf16 sA[4 * BM * 32];
    __shared__ __bf16 sB[4 * BN * 32];
    __shared__ __bf16 sE[(MODE == 0) ? 64 * 72 : 1];
    int bm = blockIdx.x, bn = blockIdx.y;
    int tid = threadIdx.x, w = tid >> 6, l = tid & 63;
    int wr = (w >> 1) * (16 * MI), wc = (w & 1) * (16 * NI);
    int r = tid >> 2, c = (tid & 3) * 8;
    f32x4 acc[MI][NI] = {};
    const int nt = K / 32;

    auto stage = [&](int t, int buf) {
        int k0 = t * 32;
#pragma unroll
        for (int i = 0; i < LA; i++)
            gload16(&A[(size_t)(bm * BM + i * 64 + r) * K + k0 + c],
                    &sA[buf * (BM * 32) + i * 2048 + w * 512]);
#pragma unroll
        for (int i = 0; i < LB; i++)
            gload16(&Bw[(size_t)(bn * BN + i * 64 + r) * K + k0 + c],
                    &sB[buf * (BN * 32) + i * 2048 + w * 512]);
    };

    stage(0, 0);
    stage(1, 1);
    stage(2, 2);
    for (int t = 0; t < nt; t++) {
        if (t + 2 < nt) {
            if constexpr (L == 2) asm volatile("s_waitcnt vmcnt(4)" ::: "memory");
            else asm volatile("s_waitcnt vmcnt(6)" ::: "memory");
        } else if (t + 1 < nt) {
            if constexpr (L == 2) asm volatile("s_waitcnt vmcnt(2)" ::: "memory");
            else asm volatile("s_waitcnt vmcnt(3)" ::: "memory");
        } else {
            asm volatile("s_waitcnt vmcnt(0)" ::: "memory");
        }
        asm volatile("s_barrier" ::: "memory");
        if (t + 3 < nt) stage(t + 3, (t + 3) & 3);
        int buf = t & 3;
        bf16x8 af[MI], bfr[NI];
#pragma unroll
        for (int mi = 0; mi < MI; mi++)
            af[mi] = *(const bf16x8*)&sA[buf * (BM * 32) + (wr + mi * 16 + (l & 15)) * 32 + ((l >> 4) << 3)];
#pragma unroll
        for (int ni = 0; ni < NI; ni++)
            bfr[ni] = *(const bf16x8*)&sB[buf * (BN * 32) + (wc + ni * 16 + (l & 15)) * 32 + ((l >> 4) << 3)];
#pragma unroll
        for (int mi = 0; mi < MI; mi++)
#pragma unroll
            for (int ni = 0; ni < NI; ni++)
                acc[mi][ni] = MFMA16(af[mi], bfr[ni], acc[mi][ni]);
    }

    if (MODE == 0) {
        // qkv+xg epilogue: fragments -> sE (activation for q,k) -> coalesced stores.
        __syncthreads();
#pragma unroll
        for (int mi = 0; mi < MI; mi++)
#pragma unroll
            for (int ni = 0; ni < NI; ni++)
#pragma unroll
                for (int j = 0; j < 4; j++) {
                    int lr = wr + mi * 16 + ((l >> 4) << 2) + j;
                    int lc = wc + ni * 16 + (l & 15);
                    float v = acc[mi][ni][j];
                    if (bn < 16) v = elu1(v);  // q,k get feature map
                    sE[lr * 72 + lc] = (__bf16)v;
                }
        __syncthreads();
        int which = bn >> 3;  // 0:q 1:k 2:v 3:xg
        int b = bm >> 4, s0b = (bm & 15) * 64, h = bn & 7;
        int bh = b * 8 + h;
        if (which == 0 || which == 1) {
            __bf16* qk = (which == 0 ? q_out : k_out) + ((size_t)(bh * 1024 + s0b)) * 64;
#pragma unroll
            for (int p = 0; p < 2; p++) {
                int idx = p * 256 + tid;
                *(bf16x8*)&qk[idx * 8] = *(const bf16x8*)&sE[(idx >> 3) * 72 + (idx & 7) * 8];
            }
        }
        if (which == 1 || which == 2) {
            __bf16* tdst = (which == 1 ? kt_out : vt_out) + (size_t)(bh * 64) * 1024 + s0b;
            alignas(16) __bf16 tmp[16];
#pragma unroll
            for (int sj = 0; sj < 16; sj++) tmp[sj] = sE[(w * 16 + sj) * 72 + l];
            *(bf16x8*)&tdst[(size_t)l * 1024 + w * 16] = *(const bf16x8*)&tmp[0];
            *(bf16x8*)&tdst[(size_t)l * 1024 + w * 16 + 8] = *(const bf16x8*)&tmp[8];
        }
        if (which == 3) {
            __bf16* dst = xg_out + (size_t)(bm * 64) * 512 + (bn - 24) * 64;
#pragma unroll
            for (int p = 0; p < 2; p++) {
                int idx = p * 256 + tid;
                *(bf16x8*)&dst[(size_t)(idx >> 3) * 512 + (idx & 7) * 8] =
                    *(const bf16x8*)&sE[(idx >> 3) * 72 + (idx & 7) * 8];
            }
        }
    } else {
#pragma unroll
        for (int mi = 0; mi < MI; mi++)
#pragma unroll
            for (int ni = 0; ni < NI; ni++)
#pragma unroll
                for (int j = 0; j < 4; j++) {
                    int gm = bm * BM + wr + mi * 16 + ((l >> 4) << 2) + j;
                    int gn = bn * BN + wc + ni * 16 + (l & 15);
                    if (MODE == 1) {
                        float v = acc[mi][ni][j] + bias[gn];
                        outb[(size_t)gm * 512 + gn] = (__bf16)v;
                    } else {
                        float v = acc[mi][ni][j] + (float)xgb[(size_t)gm * 512 + gn] + bias[gn];
                        float g = 1.f / (1.f + __expf(-v));
                        float xv = xf[(size_t)gm * 512 + gn];
                        float pv = (float)pvb[(size_t)gm * 512 + gn];
                        outf[(size_t)gm * 512 + gn] = xv + g * (pv - xv);
                    }
                }
    }
}

// ---------------------------------------------------------------- per-chunk M_c = V^T K + ksum_c (128 blocks)
__global__ __launch_bounds__(256) void mc_kernel(const __bf16* __restrict__ ktb,
                                                 const __bf16* __restrict__ vtb,
                                                 float* __restrict__ Mc, float* __restrict__ ksc) {
    int blk = blockIdx.x;
    int bh = blk >> 3, ch = blk & 7;
    int tid = threadIdx.x, w = tid >> 6, l = tid & 63;
    const __bf16* vb = vtb + (size_t)bh * 65536 + ch * 128;
    const __bf16* kp = ktb + (size_t)bh * 65536 + ch * 128;
    f32x4 macc[4] = {};
#pragma unroll
    for (int ks = 0; ks < 4; ks++) {
        bf16x8 a = *(const bf16x8*)&vb[(size_t)(w * 16 + (l & 15)) * 1024 + ks * 32 + ((l >> 4) << 3)];
#pragma unroll
        for (int ni = 0; ni < 4; ni++) {
            bf16x8 bb = *(const bf16x8*)&kp[(size_t)(ni * 16 + (l & 15)) * 1024 + ks * 32 + ((l >> 4) << 3)];
            macc[ni] = MFMA16(a, bb, macc[ni]);
        }
    }
    float* mout = Mc + (size_t)blk * 4096;
#pragma unroll
    for (int ni = 0; ni < 4; ni++)
#pragma unroll
        for (int j = 0; j < 4; j++)
            mout[(size_t)(w * 16 + ((l >> 4) << 2) + j) * 64 + ni * 16 + (l & 15)] = macc[ni][j];
    if (tid < 64) {
        float s = 0.f;
        const __bf16* kr = ktb + (size_t)(bh * 64 + tid) * 1024 + ch * 128;
#pragma unroll
        for (int t = 0; t < 16; t++) {
            bf16x8 v = *(const bf16x8*)&kr[t * 8];
#pragma unroll
            for (int j = 0; j < 8; j++) s += (float)v[j];
        }
        ksc[blk * 64 + tid] = s;
    }
}

// ---------------------------------------------------------------- attention: 256 blocks (bh, ch, half)
__global__ __launch_bounds__(256) void attn_kernel(
    const __bf16* __restrict__ qb, const __bf16* __restrict__ kb,
    const __bf16* __restrict__ vtb, const float* __restrict__ Mc,
    const float* __restrict__ ksc, __bf16* __restrict__ attn_out) {
    int blk = blockIdx.x;
    int bh = blk >> 4, ch = (blk >> 1) & 7, half = blk & 1;
    int b = bh >> 3, h = bh & 7;
    int tid = threadIdx.x, w = tid >> 6, l = tid & 63;

    __shared__ __bf16 sQ[64 * 72];
    __shared__ __bf16 sP[64 * 136];
    __shared__ __bf16 sM[64 * 72];
    __shared__ float den[64];
    __shared__ float rsum[64];
    __shared__ float ksst[64];

    const __bf16* qsrc = qb + (size_t)(bh * 1024 + ch * 128 + half * 64) * 64;
#pragma unroll
    for (int i = 0; i < 2; i++) {
        int e = i * 2048 + tid * 8;
        *(bf16x8*)&sQ[(e >> 6) * 72 + (e & 63)] = *(const bf16x8*)&qsrc[e];
    }
    {
        int r0 = tid >> 2, c0 = (tid & 3) * 16;
        f32x4 s0 = {}, s1 = {}, s2 = {}, s3 = {};
        const float* mcb = Mc + (size_t)(bh * 8) * 4096 + r0 * 64 + c0;
        for (int c = 0; c < ch; c++) {
            const float* p = mcb + (size_t)c * 4096;
            s0 += *(const f32x4*)&p[0];
            s1 += *(const f32x4*)&p[4];
            s2 += *(const f32x4*)&p[8];
            s3 += *(const f32x4*)&p[12];
        }
        __bf16* d = &sM[r0 * 72 + c0];
#pragma unroll
        for (int j = 0; j < 4; j++) {
            d[j] = (__bf16)s0[j];
            d[4 + j] = (__bf16)s1[j];
            d[8 + j] = (__bf16)s2[j];
            d[12 + j] = (__bf16)s3[j];
        }
    }
    if (tid < 64) {
        float s = 0.f;
        for (int c = 0; c < ch; c++) s += ksc[(bh * 8 + c) * 64 + tid];
        ksst[tid] = s;
    }
    __syncthreads();

    if (tid < 64) {
        float s = 0.f;
#pragma unroll
        for (int d0 = 0; d0 < 64; d0 += 8) {
            bf16x8 qv = *(const bf16x8*)&sQ[tid * 72 + d0];
#pragma unroll
            for (int jj = 0; jj < 8; jj++) s += (float)qv[jj] * ksst[d0 + jj];
        }
        den[tid] = s;
    }

    {
        int wr = w * 16;
        const int CFMAX = half ? (w + 4) : w;
        const int CFLIM = half ? 7 : 3;
        const __bf16* kbase = kb + (size_t)(bh * 1024 + ch * 128) * 64;
        bf16x8 aq[2];
#pragma unroll
        for (int ks = 0; ks < 2; ks++)
            aq[ks] = *(const bf16x8*)&sQ[(wr + (l & 15)) * 72 + ks * 32 + ((l >> 4) << 3)];
        f32x4 acc[8] = {};
#pragma unroll
        for (int cf = 0; cf < 8; cf++) {
            if (cf <= CFMAX && cf <= CFLIM) {
#pragma unroll
                for (int ks = 0; ks < 2; ks++) {
                    bf16x8 bfr = *(const bf16x8*)&kbase[(size_t)(cf * 16 + (l & 15)) * 64 + ks * 32 + ((l >> 4) << 3)];
                    acc[cf] = MFMA16(aq[ks], bfr, acc[cf]);
                }
            }
        }
#pragma unroll
        for (int j = 0; j < 4; j++) {
            int lrow = wr + ((l >> 4) << 2) + j;
            int grow = half * 64 + lrow;
            float rs = 0.f;
#pragma unroll
            for (int cf = 0; cf < 8; cf++) {
                if (cf <= CFMAX && cf <= CFLIM) {
                    int col = cf * 16 + (l & 15);
                    float v = acc[cf][j];
                    v = (col <= grow) ? v : 0.f;
                    rs += v;
                    sP[lrow * 136 + col] = (__bf16)v;
                }
            }
            if (CFMAX + 1 <= CFLIM) sP[lrow * 136 + (CFMAX + 1) * 16 + (l & 15)] = (__bf16)0.f;
#pragma unroll
            for (int off = 1; off < 16; off <<= 1) rs += __shfl_xor(rs, off);
            if ((l & 15) == 0) rsum[lrow] = rs;
        }
    }
    __syncthreads();

    f32x4 o[4] = {};
    {
        int wr = w * 16;
        int ksmax = half ? (2 + (w >> 1)) : (w >> 1);
        const __bf16* vbase = vtb + (size_t)bh * 65536 + ch * 128;
#pragma unroll
        for (int ks = 0; ks < 4; ks++) {
            if (ks <= ksmax) {
                bf16x8 a = *(const bf16x8*)&sP[(wr + (l & 15)) * 136 + ks * 32 + ((l >> 4) << 3)];
#pragma unroll
                for (int ni = 0; ni < 4; ni++) {
                    bf16x8 bfr = *(const bf16x8*)&vbase[(size_t)(ni * 16 + (l & 15)) * 1024 + ks * 32 + ((l >> 4) << 3)];
                    o[ni] = MFMA16(a, bfr, o[ni]);
                }
            }
        }
        if (ch > 0) {
#pragma unroll
            for (int ks = 0; ks < 2; ks++) {
                bf16x8 a = *(const bf16x8*)&sQ[(wr + (l & 15)) * 72 + ks * 32 + ((l >> 4) << 3)];
#pragma unroll
                for (int ni = 0; ni < 4; ni++) {
                    bf16x8 bfr = *(const bf16x8*)&sM[(ni * 16 + (l & 15)) * 72 + ks * 32 + ((l >> 4) << 3)];
                    o[ni] = MFMA16(a, bfr, o[ni]);
                }
            }
        }
    }

    __bf16* obase = attn_out + ((size_t)(b * 1024 + ch * 128 + half * 64)) * 512 + h * 64;
#pragma unroll
    for (int j = 0; j < 4; j++) {
        int lrow = w * 16 + ((l >> 4) << 2) + j;
        float dn = den[lrow] + rsum[lrow] + 1e-6f;
#pragma unroll
        for (int ni = 0; ni < 4; ni++) {
            int col = ni * 16 + (l & 15);
            obase[(size_t)lrow * 512 + col] = (__bf16)(o[ni][j] / dn);
        }
    }
}

// ----------------------------------------------------------------
extern "C" void kernel_launch(void* const* d_in, const int* in_sizes, int n_in,
                              void* d_out, int out_size, void* d_ws, size_t ws_size,
                              hipStream_t stream) {
    const float* x = (const float*)d_in[0];
    const float* Wq = (const float*)d_in[1];
    const float* Wk = (const float*)d_in[2];
    const float* Wv = (const float*)d_in[3];
    const float* Wo = (const float*)d_in[4];
    const float* bo = (const float*)d_in[5];
    const float* Wg = (const float*)d_in[6];
    const float* bg = (const float*)d_in[7];
    float* out = (float*)d_out;

    char* ws = (char*)d_ws;
    size_t off = 0;
    auto alloc = [&](size_t bytes) -> void* {
        void* p = ws + off;
        off += (bytes + 255) & ~(size_t)255;
        return p;
    };
    __bf16* xb    = (__bf16*)alloc((size_t)2048 * 512 * 2);
    __bf16* wqkvT = (__bf16*)alloc((size_t)2048 * 512 * 2);   // q,k,v,wg1 columns (B^T)
    __bf16* woT   = (__bf16*)alloc((size_t)512 * 512 * 2);
    __bf16* wg2T  = (__bf16*)alloc((size_t)512 * 512 * 2);
    __bf16* qb    = (__bf16*)alloc((size_t)16 * 1024 * 64 * 2);
    __bf16* kb    = (__bf16*)alloc((size_t)16 * 1024 * 64 * 2);
    __bf16* ktb   = (__bf16*)alloc((size_t)16 * 64 * 1024 * 2);
    __bf16* vtb   = (__bf16*)alloc((size_t)16 * 64 * 1024 * 2);
    float*  Mc    = (float*)alloc((size_t)128 * 4096 * 4);
    float*  ksc   = (float*)alloc((size_t)128 * 64 * 4);
    __bf16* attn  = (__bf16*)alloc((size_t)2048 * 512 * 2);
    __bf16* projb = (__bf16*)alloc((size_t)2048 * 512 * 2);
    __bf16* xgb   = (__bf16*)alloc((size_t)2048 * 512 * 2);

    prep_kernel<<<dim3(16, 32, 6), 256, 0, stream>>>(x, Wq, Wk, Wv, Wo, Wg, xb, wqkvT, woT, wg2T);
    gemm_kernel<0, 64, 64><<<dim3(32, 32), 256, 0, stream>>>(
        xb, wqkvT, nullptr, nullptr, nullptr, nullptr, nullptr, nullptr,
        qb, kb, ktb, vtb, xgb, 512);
    mc_kernel<<<128, 256, 0, stream>>>(ktb, vtb, Mc, ksc);
    attn_kernel<<<256, 256, 0, stream>>>(qb, kb, vtb, Mc, ksc, attn);
    gemm_kernel<1, 64, 64><<<dim3(32, 8), 256, 0, stream>>>(
        attn, woT, bo, nullptr, nullptr, nullptr, nullptr, projb,
        nullptr, nullptr, nullptr, nullptr, nullptr, 512);
    gemm_kernel<2, 64, 64><<<dim3(32, 8), 256, 0, stream>>>(
        projb, wg2T, bg, x, xgb, projb, out, nullptr,
        nullptr, nullptr, nullptr, nullptr, nullptr, 512);
}